// Round 12
// baseline (151.328 us; speedup 1.0000x reference)
//
#include <hip/hip_runtime.h>
#include <math.h>

#define D_MODEL 1024
#define SEQ     2048
#define BATCH   4
#define NROWS   (BATCH * SEQ)   // 8192

typedef short bf16x8 __attribute__((ext_vector_type(8)));
typedef float f32x4  __attribute__((ext_vector_type(4)));

// f32 -> bf16 round-to-nearest-even
static __device__ __forceinline__ unsigned short f2bf(float f) {
    unsigned int x = __float_as_uint(f);
    x += 0x7FFFu + ((x >> 16) & 1u);
    return (unsigned short)(x >> 16);
}

// ---------------------------------------------------------------------------
// Kernel 1: pack W -> Wb[192][1024] bf16, coalesced reads + LDS transpose.
// ---------------------------------------------------------------------------
__global__ __launch_bounds__(256) void w_pack(
    const float* __restrict__ Wq, const float* __restrict__ Wk,
    const float* __restrict__ Wv, unsigned short* __restrict__ Wb)
{
    __shared__ float st[64][68];
    const int mat = blockIdx.x >> 4;
    const int k0  = (blockIdx.x & 15) * 64;
    const float* W = (mat == 0) ? Wq : (mat == 1) ? Wk : Wv;
    const int t  = threadIdx.x;
    const int kr = t >> 2, cs = (t & 3) * 16;
#pragma unroll
    for (int i = 0; i < 4; ++i)
        *(float4*)&st[kr][cs + i * 4] = *(const float4*)&W[(size_t)(k0 + kr) * 64 + cs + i * 4];
    __syncthreads();
    const int c = t >> 2, ks = (t & 3) * 16;
    unsigned short tmp[16];
#pragma unroll
    for (int j = 0; j < 16; ++j) tmp[j] = f2bf(st[ks + j][c]);
    *(uint4*)&Wb[(size_t)(mat * 64 + c) * D_MODEL + k0 + ks]     = *(uint4*)&tmp[0];
    *(uint4*)&Wb[(size_t)(mat * 64 + c) * D_MODEL + k0 + ks + 8] = *(uint4*)&tmp[8];
}

// ---------------------------------------------------------------------------
// Kernel 2: QKV projection via MFMA.  BM=32, BN=96, BK=64.
// grid (256, 2) x 128 thr (2 waves; wave tile 32x48 = 2x3 frags)
// -> 512 blocks = 2 blocks/CU: one block's barrier drain overlaps the
// other's compute. __launch_bounds__(128, 2) -> VGPR budget 256 so the 10
// staged loads (4 float4 A + 6 uint4 B) stay live.
// Loop: {barrA; ds_write(t); barrB; issue loads(t+1); compute(t)}.
// Epilogue: acc -> f32 LDS stage -> dense bf16 stores (V transposed).
// q pre-scaled by 0.125*log2(e): attention softmax runs in exp2 domain.
// ---------------------------------------------------------------------------
__global__ __launch_bounds__(128, 2) void qkv_proj_mfma(
    const float* __restrict__ x, const unsigned short* __restrict__ Wb,
    const float* __restrict__ bq, const float* __restrict__ bk,
    const float* __restrict__ bv,
    unsigned short* __restrict__ qb, unsigned short* __restrict__ kb,
    unsigned short* __restrict__ Vt)
{
    __shared__ float smem[4608];                       // 18.4 KB, reused
    unsigned short* A_lds = (unsigned short*)smem;     // [32][72]
    unsigned short* B_lds = A_lds + 32 * 72;           // [96][72]

    const int tid  = threadIdx.x;
    const int wc   = tid >> 6;          // wave id: col half 0..1
    const int lane = tid & 63;
    const int lg   = lane >> 4;         // 0..3
    const int lc   = lane & 15;         // 0..15
    const int m0   = blockIdx.x * 32;
    const int n0   = blockIdx.y * 96;
    const int by   = blockIdx.y;

    f32x4 acc[2][3];
#pragma unroll
    for (int mf = 0; mf < 2; ++mf)
#pragma unroll
        for (int nf = 0; nf < 3; ++nf) acc[mf][nf] = (f32x4){0.f, 0.f, 0.f, 0.f};

    // staging: A rows (tid>>3) and +16, slot tid&7; B rows (tid>>3)+16i
    const int arow = tid >> 3, ac8 = tid & 7;
    float4 a0[2], a1[2];
    uint4  brg[6];

    {   // prologue: k0 = 0
#pragma unroll
        for (int i = 0; i < 2; ++i) {
            const float* ap = &x[(size_t)(m0 + arow + 16 * i) * D_MODEL + ac8 * 8];
            a0[i] = *(const float4*)ap;
            a1[i] = *(const float4*)(ap + 4);
        }
#pragma unroll
        for (int i = 0; i < 6; ++i)
            brg[i] = *(const uint4*)&Wb[(size_t)(n0 + arow + 16 * i) * D_MODEL + ac8 * 8];
    }

    for (int it = 0; it < 16; ++it) {
        __syncthreads();                 // barrA: LDS free; collects loads(t)
#pragma unroll
        for (int i = 0; i < 2; ++i) {
            unsigned int w0 = f2bf(a0[i].x) | ((unsigned)f2bf(a0[i].y) << 16);
            unsigned int w1 = f2bf(a0[i].z) | ((unsigned)f2bf(a0[i].w) << 16);
            unsigned int w2 = f2bf(a1[i].x) | ((unsigned)f2bf(a1[i].y) << 16);
            unsigned int w3 = f2bf(a1[i].z) | ((unsigned)f2bf(a1[i].w) << 16);
            *(uint4*)&A_lds[(arow + 16 * i) * 72 + ac8 * 8] = make_uint4(w0, w1, w2, w3);
        }
#pragma unroll
        for (int i = 0; i < 6; ++i)
            *(uint4*)&B_lds[(arow + 16 * i) * 72 + ac8 * 8] = brg[i];
        __syncthreads();                 // barrB: LDS ready

        if (it < 15) {                   // issue loads(t+1): hide under compute
            const int k0 = (it + 1) * 64;
#pragma unroll
            for (int i = 0; i < 2; ++i) {
                const float* ap = &x[(size_t)(m0 + arow + 16 * i) * D_MODEL + k0 + ac8 * 8];
                a0[i] = *(const float4*)ap;
                a1[i] = *(const float4*)(ap + 4);
            }
#pragma unroll
            for (int i = 0; i < 6; ++i)
                brg[i] = *(const uint4*)&Wb[(size_t)(n0 + arow + 16 * i) * D_MODEL + k0 + ac8 * 8];
        }

#pragma unroll
        for (int kk = 0; kk < 2; ++kk) {
            bf16x8 af[2], bfr[3];
#pragma unroll
            for (int mf = 0; mf < 2; ++mf)
                af[mf] = *(const bf16x8*)&A_lds[(mf * 16 + lc) * 72 + kk * 32 + lg * 8];
#pragma unroll
            for (int nf = 0; nf < 3; ++nf)
                bfr[nf] = *(const bf16x8*)&B_lds[(wc * 48 + nf * 16 + lc) * 72 + kk * 32 + lg * 8];
#pragma unroll
            for (int mf = 0; mf < 2; ++mf)
#pragma unroll
                for (int nf = 0; nf < 3; ++nf)
                    acc[mf][nf] = __builtin_amdgcn_mfma_f32_16x16x32_bf16(
                        af[mf], bfr[nf], acc[mf][nf], 0, 0, 0);
        }
    }

    // ---- epilogue: stage acc (f32) in LDS, then dense writes ----
    __syncthreads();
    float* st = smem;                    // [32][100]
#pragma unroll
    for (int mf = 0; mf < 2; ++mf)
#pragma unroll
        for (int nf = 0; nf < 3; ++nf)
#pragma unroll
            for (int r = 0; r < 4; ++r)
                st[(mf * 16 + lg * 4 + r) * 100 + wc * 48 + nf * 16 + lc] = acc[mf][nf][r];
    __syncthreads();

    unsigned short tmp[16];
    const float QSCALE = 0.125f * 1.4426950408889634f;   // exp2-domain softmax
    if (by == 0) {
        // q: local cols 0..63 (32 rows x 4 col-groups = 128 units)
        {
            const int row = tid >> 2, c16 = (tid & 3) * 16;
#pragma unroll
            for (int j = 0; j < 16; ++j)
                tmp[j] = f2bf((st[row * 100 + c16 + j] + bq[c16 + j]) * QSCALE);
            unsigned short* dst = &qb[(size_t)(m0 + row) * 64 + c16];
            *(uint4*)dst       = *(uint4*)&tmp[0];
            *(uint4*)(dst + 8) = *(uint4*)&tmp[8];
        }
        // k cols 0..31: local cols 64..95 (32 rows x 2 groups = 64 units)
        if (tid < 64) {
            const int row = tid >> 1, c16 = (tid & 1) * 16;
#pragma unroll
            for (int j = 0; j < 16; ++j)
                tmp[j] = f2bf(st[row * 100 + 64 + c16 + j] + bk[c16 + j]);
            unsigned short* dst = &kb[(size_t)(m0 + row) * 64 + c16];
            *(uint4*)dst       = *(uint4*)&tmp[0];
            *(uint4*)(dst + 8) = *(uint4*)&tmp[8];
        }
    } else {
        // k cols 32..63: local cols 0..31
        if (tid < 64) {
            const int row = tid >> 1, c16 = (tid & 1) * 16;
#pragma unroll
            for (int j = 0; j < 16; ++j)
                tmp[j] = f2bf(st[row * 100 + c16 + j] + bk[32 + c16 + j]);
            unsigned short* dst = &kb[(size_t)(m0 + row) * 64 + 32 + c16];
            *(uint4*)dst       = *(uint4*)&tmp[0];
            *(uint4*)(dst + 8) = *(uint4*)&tmp[8];
        }
        // v: local cols 32..95 -> Vt[d][seq] (64 d x 2 seq-groups = 128 units)
        {
            const int d = tid >> 1, s16 = (tid & 1) * 16;
            const float bs = bv[d];
#pragma unroll
            for (int j = 0; j < 16; ++j)
                tmp[j] = f2bf(st[(s16 + j) * 100 + 32 + d] + bs);
            const int bb = m0 >> 11, seq0 = m0 & 2047;
            unsigned short* dst = &Vt[((size_t)(bb * 64 + d)) * SEQ + seq0 + s16];
            *(uint4*)dst       = *(uint4*)&tmp[0];
            *(uint4*)(dst + 8) = *(uint4*)&tmp[8];
        }
    }
}

// ---------------------------------------------------------------------------
// Kernel 3: causal flash attention partials — single wave, no barriers,
// direct-global K/V frags with cross-tile register prefetch; exp2-domain
// softmax (q pre-scaled by log2 e). Heavy q-tiles dispatched first.
// __launch_bounds__(64, 2): 256-VGPR budget keeps kr[8]+vr[8] live.
// ---------------------------------------------------------------------------
__global__ __launch_bounds__(64, 2) void attn_partial(
    const unsigned short* __restrict__ qb, const unsigned short* __restrict__ kb,
    const unsigned short* __restrict__ Vt,
    float* __restrict__ O_part, float* __restrict__ ml)
{
    __shared__ unsigned short P_lds[16 * 72];

    const int qt = (int)gridDim.x - 1 - (int)blockIdx.x;   // heavy first
    const int ch = blockIdx.y;
    const int b  = blockIdx.z;
    const int lane = threadIdx.x;
    const int lg = lane >> 4, lc = lane & 15;

    int nt = ((qt * 16 + 15 - ch * 512) >> 6) + 1;
    if (nt > 8) nt = 8;
    if (nt <= 0) return;                       // block-uniform exit

    const size_t qrow = (size_t)(b * SEQ + qt * 16 + lc);
    bf16x8 qf0 = *(const bf16x8*)&qb[qrow * 64 + lg * 8];
    bf16x8 qf1 = *(const bf16x8*)&qb[qrow * 64 + 32 + lg * 8];

    f32x4 O[4];
#pragma unroll
    for (int df = 0; df < 4; ++df) O[df] = (f32x4){0.f, 0.f, 0.f, 0.f};
    float m[4] = {-1e30f, -1e30f, -1e30f, -1e30f};
    float l[4] = {0.f, 0.f, 0.f, 0.f};

    const int rowbase = qt * 16 + lg * 4;

    bf16x8 kr[8], vr[8];
    {   // prologue: tile 0 K+V
        const int kb0 = ch * 512;
#pragma unroll
        for (int kf = 0; kf < 4; ++kf) {
            const unsigned short* kp = &kb[((size_t)(b * SEQ + kb0 + kf * 16 + lc)) * 64];
            kr[kf * 2]     = *(const bf16x8*)&kp[lg * 8];
            kr[kf * 2 + 1] = *(const bf16x8*)&kp[32 + lg * 8];
            const unsigned short* vp = &Vt[((size_t)(b * 64 + kf * 16 + lc)) * SEQ + kb0];
            vr[kf * 2]     = *(const bf16x8*)&vp[lg * 8];
            vr[kf * 2 + 1] = *(const bf16x8*)&vp[32 + lg * 8];
        }
    }

    for (int t = 0; t < nt; ++t) {
        const int kb0 = ch * 512 + t * 64;

        // QK^T from kr (scores already in log2 domain via q pre-scale)
        f32x4 s[4];
#pragma unroll
        for (int kf = 0; kf < 4; ++kf) {
            f32x4 z = (f32x4){0.f, 0.f, 0.f, 0.f};
            z = __builtin_amdgcn_mfma_f32_16x16x32_bf16(qf0, kr[kf * 2], z, 0, 0, 0);
            s[kf] = __builtin_amdgcn_mfma_f32_16x16x32_bf16(qf1, kr[kf * 2 + 1], z, 0, 0, 0);
        }
        // prefetch K for t+1
        if (t + 1 < nt) {
            const int kb0n = kb0 + 64;
#pragma unroll
            for (int kf = 0; kf < 4; ++kf) {
                const unsigned short* kp = &kb[((size_t)(b * SEQ + kb0n + kf * 16 + lc)) * 64];
                kr[kf * 2]     = *(const bf16x8*)&kp[lg * 8];
                kr[kf * 2 + 1] = *(const bf16x8*)&kp[32 + lg * 8];
            }
        }

        // online softmax (exp2); D-layout: key = kb0+kf*16+lc, row = rowbase+r
#pragma unroll
        for (int r = 0; r < 4; ++r) {
            float tm = -1e30f;
#pragma unroll
            for (int kf = 0; kf < 4; ++kf) {
                float sv = s[kf][r];
                if (kb0 + kf * 16 + lc > rowbase + r) sv = -1e30f;
                s[kf][r] = sv;
                tm = fmaxf(tm, sv);
            }
            tm = fmaxf(tm, __shfl_xor(tm, 1));
            tm = fmaxf(tm, __shfl_xor(tm, 2));
            tm = fmaxf(tm, __shfl_xor(tm, 4));
            tm = fmaxf(tm, __shfl_xor(tm, 8));
            float mn  = fmaxf(m[r], tm);
            float fac = exp2f(m[r] - mn);
            float ts  = 0.f;
#pragma unroll
            for (int kf = 0; kf < 4; ++kf) {
                float p = exp2f(s[kf][r] - mn);
                ts += p;
                P_lds[(lg * 4 + r) * 72 + kf * 16 + lc] = f2bf(p);
            }
            ts += __shfl_xor(ts, 1);
            ts += __shfl_xor(ts, 2);
            ts += __shfl_xor(ts, 4);
            ts += __shfl_xor(ts, 8);
            l[r] = l[r] * fac + ts;
            m[r] = mn;
            O[0][r] *= fac; O[1][r] *= fac; O[2][r] *= fac; O[3][r] *= fac;
        }

        // PV from vr (P via same-wave LDS relayout)
        bf16x8 pf0 = *(const bf16x8*)&P_lds[lc * 72 + lg * 8];
        bf16x8 pf1 = *(const bf16x8*)&P_lds[lc * 72 + 32 + lg * 8];
#pragma unroll
        for (int df = 0; df < 4; ++df) {
            O[df] = __builtin_amdgcn_mfma_f32_16x16x32_bf16(pf0, vr[df * 2],     O[df], 0, 0, 0);
            O[df] = __builtin_amdgcn_mfma_f32_16x16x32_bf16(pf1, vr[df * 2 + 1], O[df], 0, 0, 0);
        }
        // prefetch V for t+1
        if (t + 1 < nt) {
            const int kb0n = kb0 + 64;
#pragma unroll
            for (int df = 0; df < 4; ++df) {
                const unsigned short* vp = &Vt[((size_t)(b * 64 + df * 16 + lc)) * SEQ + kb0n];
                vr[df * 2]     = *(const bf16x8*)&vp[lg * 8];
                vr[df * 2 + 1] = *(const bf16x8*)&vp[32 + lg * 8];
            }
        }
    }

    const int slot = (b * 128 + qt) * 4 + ch;
    float* Op = O_part + (size_t)slot * 1024;
#pragma unroll
    for (int df = 0; df < 4; ++df)
#pragma unroll
        for (int r = 0; r < 4; ++r)
            Op[(lg * 4 + r) * 64 + df * 16 + lc] = O[df][r];
    if (lc == 0) {
#pragma unroll
        for (int r = 0; r < 4; ++r) {
            ml[slot * 32 + lg * 4 + r]      = m[r];
            ml[slot * 32 + 16 + lg * 4 + r] = l[r];
        }
    }
}

// ---------------------------------------------------------------------------
// Kernel 4: merge chunk partials -> final output (f32).  exp2 domain.
// ---------------------------------------------------------------------------
__global__ __launch_bounds__(256) void attn_merge(
    const float* __restrict__ O_part, const float* __restrict__ ml,
    float* __restrict__ out)
{
    int idx = blockIdx.x * 256 + threadIdx.x;   // 262144 threads, 2 f32 each
    int row = idx >> 5;
    int d0  = (idx & 31) * 2;
    int b = row >> 11, seq = row & 2047;
    int qt = seq >> 4, rl = seq & 15;
    int nc = ((qt * 16 + 15) >> 9) + 1;         // active chunks, 1..4
    int sb = (b * 128 + qt) * 4;

    float M = -1e30f;
    for (int c = 0; c < nc; ++c) M = fmaxf(M, ml[(sb + c) * 32 + rl]);
    float L = 0.f, o0 = 0.f, o1 = 0.f;
    for (int c = 0; c < nc; ++c) {
        float e = exp2f(ml[(sb + c) * 32 + rl] - M);
        L += e * ml[(sb + c) * 32 + 16 + rl];
        const float* Op = O_part + (size_t)(sb + c) * 1024 + rl * 64 + d0;
        o0 += e * Op[0];
        o1 += e * Op[1];
    }
    float inv = 1.f / L;
    *(float2*)&out[(size_t)row * 64 + d0] = make_float2(o0 * inv, o1 * inv);
}

// ---------------------------------------------------------------------------
extern "C" void kernel_launch(void* const* d_in, const int* in_sizes, int n_in,
                              void* d_out, int out_size, void* d_ws, size_t ws_size,
                              hipStream_t stream)
{
    (void)in_sizes; (void)n_in; (void)out_size; (void)ws_size;

    const float* x  = (const float*)d_in[0];
    const float* Wq = (const float*)d_in[1];
    const float* bq = (const float*)d_in[2];
    const float* Wk = (const float*)d_in[3];
    const float* bk = (const float*)d_in[4];
    const float* Wv = (const float*)d_in[5];
    const float* bv = (const float*)d_in[6];
    float* out = (float*)d_out;

    // workspace layout (bytes):
    // Wb 393216 | qb 1M | kb 1M | Vt 1M | ml 262144 | O_part 8M  (~12.2 MB)
    char* ws = (char*)d_ws;
    unsigned short* Wb = (unsigned short*)(ws);
    unsigned short* qb = (unsigned short*)(ws + 393216);
    unsigned short* kb = (unsigned short*)(ws + 393216 + 1048576);
    unsigned short* Vt = (unsigned short*)(ws + 393216 + 2 * 1048576);
    float*          ml = (float*)(ws + 393216 + 3 * 1048576);
    float*      O_part = (float*)(ws + 393216 + 3 * 1048576 + 262144);

    w_pack<<<48, 256, 0, stream>>>(Wq, Wk, Wv, Wb);
    qkv_proj_mfma<<<dim3(256, 2), 128, 0, stream>>>(x, Wb, bq, bk, bv, qb, kb, Vt);
    attn_partial<<<dim3(128, 4, 4), 64, 0, stream>>>(qb, kb, Vt, O_part, ml);
    attn_merge<<<1024, 256, 0, stream>>>(O_part, ml, out);
}